// Round 1
// baseline (1156.160 us; speedup 1.0000x reference)
//
#include <hip/hip_runtime.h>
#include <math.h>

#define EMB_DIM 256
#define NUM_EMB 2048
#define N_ROWS  65536            // 64*32*32
#define N_ELEM  16777216         // N_ROWS * EMB_DIM

// ---- workspace layout (in 4-byte elements) ----
#define IDX_OFF   0              // int[65536]
#define XSQ_OFF   65536          // float[65536]
#define ESQ_OFF   131072         // float[2048]
#define HIST_OFF  133120         // int[2048]
#define BKT_OFF   135168         // float[256]
#define WS_ELEMS  135424

// ||e||^2 per codebook column. codebook is [256][2048] row-major (d-major).
__global__ __launch_bounds__(256) void esq_k(const float* __restrict__ cb,
                                             float* __restrict__ esq) {
    int e = blockIdx.x * 256 + threadIdx.x;
    float s0 = 0.f, s1 = 0.f, s2 = 0.f, s3 = 0.f;
    for (int d = 0; d < EMB_DIM; d += 4) {
        float c0 = cb[(d + 0) * NUM_EMB + e];
        float c1 = cb[(d + 1) * NUM_EMB + e];
        float c2 = cb[(d + 2) * NUM_EMB + e];
        float c3 = cb[(d + 3) * NUM_EMB + e];
        s0 = fmaf(c0, c0, s0); s1 = fmaf(c1, c1, s1);
        s2 = fmaf(c2, c2, s2); s3 = fmaf(c3, c3, s3);
    }
    esq[e] = (s0 + s1) + (s2 + s3);
}

// ||x||^2 per row: one block per row, 256 threads (one per dim).
__global__ __launch_bounds__(256) void xsq_k(const float* __restrict__ x,
                                             float* __restrict__ xsq) {
    int row = blockIdx.x;
    int t = threadIdx.x;
    float v = x[row * EMB_DIM + t];
    float s = v * v;
    #pragma unroll
    for (int o = 32; o > 0; o >>= 1) s += __shfl_down(s, o, 64);
    __shared__ float w[4];
    if ((t & 63) == 0) w[t >> 6] = s;
    __syncthreads();
    if (t == 0) xsq[row] = (w[0] + w[1]) + (w[2] + w[3]);
}

// Distance argmin: register-tiled "GEMM" BM=64 x BN=128 x BK=16,
// 256 threads = 16(tx: col groups of 8) x 16(ty: row groups of 4).
__global__ __launch_bounds__(256) void argmin_k(const float* __restrict__ x,
                                                const float* __restrict__ cb,
                                                const float* __restrict__ xsq,
                                                const float* __restrict__ esq,
                                                int* __restrict__ idx_out) {
    __shared__ float xs[16][64];    // [k][m]
    __shared__ float cs[16][128];   // [k][j]
    __shared__ float rd[64][17];
    __shared__ int   ri[64][17];

    const int tid = threadIdx.x;
    const int tx = tid & 15;
    const int ty = tid >> 4;
    const int rowbase = blockIdx.x * 64;

    float bestd[4];
    int   besti[4];
    #pragma unroll
    for (int i = 0; i < 4; ++i) { bestd[i] = 3.4e38f; besti[i] = 0; }

    for (int et = 0; et < NUM_EMB / 128; ++et) {
        float acc[4][8];
        #pragma unroll
        for (int i = 0; i < 4; ++i)
            #pragma unroll
            for (int j = 0; j < 8; ++j) acc[i][j] = 0.f;

        for (int kt = 0; kt < EMB_DIM / 16; ++kt) {
            __syncthreads();
            {
                // stage x tile (16k x 64m), transposed store
                int m  = tid >> 2;
                int kq = (tid & 3) << 2;
                const float4 xv = *(const float4*)&x[(rowbase + m) * EMB_DIM + kt * 16 + kq];
                xs[kq + 0][m] = xv.x; xs[kq + 1][m] = xv.y;
                xs[kq + 2][m] = xv.z; xs[kq + 3][m] = xv.w;
                // stage codebook tile (16k x 128j)
                int kk = tid >> 4;
                int j8 = (tid & 15) << 3;
                const float* src = &cb[(kt * 16 + kk) * NUM_EMB + et * 128 + j8];
                const float4 c0 = *(const float4*)(src);
                const float4 c1 = *(const float4*)(src + 4);
                *(float4*)&cs[kk][j8]     = c0;
                *(float4*)&cs[kk][j8 + 4] = c1;
            }
            __syncthreads();
            #pragma unroll
            for (int k = 0; k < 16; ++k) {
                float4 xv = *(const float4*)&xs[k][ty * 4];
                float4 c0 = *(const float4*)&cs[k][tx * 8];
                float4 c1 = *(const float4*)&cs[k][tx * 8 + 4];
                float xa[4] = {xv.x, xv.y, xv.z, xv.w};
                float cc[8] = {c0.x, c0.y, c0.z, c0.w, c1.x, c1.y, c1.z, c1.w};
                #pragma unroll
                for (int i = 0; i < 4; ++i)
                    #pragma unroll
                    for (int j = 0; j < 8; ++j)
                        acc[i][j] = fmaf(xa[i], cc[j], acc[i][j]);
            }
        }
        // fold this e-tile into the running argmin (mimic reference rounding:
        // dist = (||x||^2 + ||e||^2) - 2*sim ; 2*sim is exact, so contraction ok)
        #pragma unroll
        for (int i = 0; i < 4; ++i) {
            float xq = xsq[rowbase + ty * 4 + i];
            #pragma unroll
            for (int j = 0; j < 8; ++j) {
                int e = et * 128 + tx * 8 + j;
                float d = (xq + esq[e]) - 2.0f * acc[i][j];
                if (d < bestd[i]) { bestd[i] = d; besti[i] = e; }
            }
        }
    }

    __syncthreads();
    #pragma unroll
    for (int i = 0; i < 4; ++i) {
        rd[ty * 4 + i][tx] = bestd[i];
        ri[ty * 4 + i][tx] = besti[i];
    }
    __syncthreads();
    if (tid < 64) {
        float bd = rd[tid][0];
        int   bi = ri[tid][0];
        #pragma unroll
        for (int t = 1; t < 16; ++t) {
            float d  = rd[tid][t];
            int   ii = ri[tid][t];
            if (d < bd || (d == bd && ii < bi)) { bd = d; bi = ii; }
        }
        idx_out[rowbase + tid] = bi;
    }
}

// Quantize + straight-through + loss partials + histogram. One block per row.
__global__ __launch_bounds__(256) void quant_k(const float* __restrict__ x,
                                               const float* __restrict__ cb,
                                               const int* __restrict__ idx,
                                               float* __restrict__ out,
                                               float* __restrict__ bkt,
                                               int* __restrict__ hist) {
    int row = blockIdx.x;
    int t = threadIdx.x;
    int e = idx[row];
    float q  = cb[t * NUM_EMB + e];
    float xv = x[row * EMB_DIM + t];
    out[row * EMB_DIM + t] = xv + (q - xv);   // mimic straight-through rounding
    float diff = xv - q;
    float val = diff * diff;
    #pragma unroll
    for (int o = 32; o > 0; o >>= 1) val += __shfl_down(val, o, 64);
    __shared__ float w[4];
    if ((t & 63) == 0) w[t >> 6] = val;
    __syncthreads();
    if (t == 0) {
        float s = (w[0] + w[1]) + (w[2] + w[3]);
        atomicAdd(&bkt[row & 255], s);
        atomicAdd(&hist[e], 1);
    }
}

// Finalize loss + perplexity scalars. Single block.
__global__ __launch_bounds__(256) void final_k(const float* __restrict__ bkt,
                                               const int* __restrict__ hist,
                                               float* __restrict__ out) {
    int t = threadIdx.x;
    double ls = (double)bkt[t];
    double ps = 0.0;
    for (int i = t; i < NUM_EMB; i += 256) {
        double p = (double)hist[i] / (double)N_ROWS;
        ps += p * log(p + 1e-10);
    }
    __shared__ double sd[256], sp[256];
    sd[t] = ls; sp[t] = ps;
    __syncthreads();
    for (int s = 128; s > 0; s >>= 1) {
        if (t < s) { sd[t] += sd[t + s]; sp[t] += sp[t + s]; }
        __syncthreads();
    }
    if (t == 0) {
        out[N_ELEM + 0] = (float)(1.25 * sd[0] / (double)N_ELEM);
        out[N_ELEM + 1] = (float)exp(-sp[0]);
    }
}

extern "C" void kernel_launch(void* const* d_in, const int* in_sizes, int n_in,
                              void* d_out, int out_size, void* d_ws, size_t ws_size,
                              hipStream_t stream) {
    const float* x  = (const float*)d_in[0];
    const float* cb = (const float*)d_in[1];
    float* out = (float*)d_out;

    float* ws_f = (float*)d_ws;
    int*   ws_i = (int*)d_ws;
    int*   idx  = ws_i + IDX_OFF;
    float* xsq  = ws_f + XSQ_OFF;
    float* esq  = ws_f + ESQ_OFF;
    int*   hist = ws_i + HIST_OFF;
    float* bkt  = ws_f + BKT_OFF;

    // zero hist + loss buckets (graph-capturable)
    hipMemsetAsync((char*)d_ws + (size_t)HIST_OFF * 4, 0,
                   (NUM_EMB + 256) * sizeof(float), stream);

    esq_k<<<NUM_EMB / 256, 256, 0, stream>>>(cb, esq);
    xsq_k<<<N_ROWS, 256, 0, stream>>>(x, xsq);
    argmin_k<<<N_ROWS / 64, 256, 0, stream>>>(x, cb, xsq, esq, idx);
    quant_k<<<N_ROWS, 256, 0, stream>>>(x, cb, idx, out, bkt, hist);
    final_k<<<1, 256, 0, stream>>>(bkt, hist, out);
}

// Round 2
// 625.697 us; speedup vs baseline: 1.8478x; 1.8478x over previous
//
#include <hip/hip_runtime.h>
#include <hip/hip_fp16.h>
#include <math.h>

#define EMB_DIM 256
#define NUM_EMB 2048
#define N_ROWS  65536            // 64*32*32
#define N_ELEM  16777216         // N_ROWS * EMB_DIM
#define EPS_GAP 1e-3f

// ---- workspace layout (in 4-byte elements) ----
#define IDX_OFF    0             // int[65536]
#define XSQ_OFF    65536         // float[65536]
#define ESQ_OFF    131072        // float[2048]
#define HIST_OFF   133120        // int[2048]
#define BKT_OFF    135168        // float[256]
#define CNT_OFF    135424        // int[1]
#define FLG_OFF    135425        // int[65536]
#define CBT_OFF    262144        // float[2048][256]  (transposed codebook)
#define CBTH_OFF   786432        // f16 [2048][256] hi plane (1 MB)
#define CBTL_OFF   1048576       // f16 [2048][256] lo plane (1 MB)
// total 1310720 floats = 5.24 MB of ws

typedef __attribute__((ext_vector_type(8))) _Float16 half8;
typedef __attribute__((ext_vector_type(4))) float f32x4;
typedef unsigned int u32;

__device__ __forceinline__ void gl_lds16(const void* g, void* l) {
    __builtin_amdgcn_global_load_lds(
        (const __attribute__((address_space(1))) u32*)g,
        (__attribute__((address_space(3))) u32*)l, 16, 0, 0);
}

// ---------- prep: ||e||^2 (same summation structure as R1 — known to match) ----------
__global__ __launch_bounds__(256) void esq_k(const float* __restrict__ cb,
                                             float* __restrict__ esq) {
    int e = blockIdx.x * 256 + threadIdx.x;
    float s0 = 0.f, s1 = 0.f, s2 = 0.f, s3 = 0.f;
    for (int d = 0; d < EMB_DIM; d += 4) {
        float c0 = cb[(d + 0) * NUM_EMB + e];
        float c1 = cb[(d + 1) * NUM_EMB + e];
        float c2 = cb[(d + 2) * NUM_EMB + e];
        float c3 = cb[(d + 3) * NUM_EMB + e];
        s0 = fmaf(c0, c0, s0); s1 = fmaf(c1, c1, s1);
        s2 = fmaf(c2, c2, s2); s3 = fmaf(c3, c3, s3);
    }
    esq[e] = (s0 + s1) + (s2 + s3);
}

// ---------- prep: transpose codebook to [2048][256] fp32 + fp16 hi/lo split ----------
__global__ __launch_bounds__(256) void prep_cbt(const float* __restrict__ cb,
                                                float* __restrict__ cbT,
                                                __half* __restrict__ cbTh,
                                                __half* __restrict__ cbTl) {
    __shared__ float lt[64][65];
    int t = threadIdx.x;
    int et = (blockIdx.x & 31) * 64;   // e-tile base
    int dt = (blockIdx.x >> 5) * 64;   // d-tile base
    #pragma unroll
    for (int p = 0; p < 4; ++p) {
        int d  = p * 16 + (t >> 4);
        int e4 = (t & 15) * 4;
        const float4 v = *(const float4*)&cb[(dt + d) * NUM_EMB + et + e4];
        lt[d][e4] = v.x; lt[d][e4 + 1] = v.y; lt[d][e4 + 2] = v.z; lt[d][e4 + 3] = v.w;
    }
    __syncthreads();
    #pragma unroll
    for (int p = 0; p < 4; ++p) {
        int e  = p * 16 + (t >> 4);
        int d4 = (t & 15) * 4;
        float a[4] = {lt[d4][e], lt[d4 + 1][e], lt[d4 + 2][e], lt[d4 + 3][e]};
        *(float4*)&cbT[(et + e) * EMB_DIM + dt + d4] = make_float4(a[0], a[1], a[2], a[3]);
        unsigned short hb[4], lb[4];
        #pragma unroll
        for (int i = 0; i < 4; ++i) {
            __half h = __float2half(a[i]);
            __half l = __float2half(a[i] - __half2float(h));
            hb[i] = __half_as_ushort(h); lb[i] = __half_as_ushort(l);
        }
        *(ushort4*)&cbTh[(et + e) * EMB_DIM + dt + d4] = make_ushort4(hb[0], hb[1], hb[2], hb[3]);
        *(ushort4*)&cbTl[(et + e) * EMB_DIM + dt + d4] = make_ushort4(lb[0], lb[1], lb[2], lb[3]);
    }
}

// ---------- prep: x -> fp16 hi/lo planes + ||x||^2 ----------
__global__ __launch_bounds__(256) void prep_x(const float* __restrict__ x,
                                              __half* __restrict__ xh,
                                              __half* __restrict__ xl,
                                              float* __restrict__ xsq) {
    int t = threadIdx.x;
    int row = blockIdx.x * 4 + (t >> 6);
    int c = (t & 63) * 4;
    const float4 v = *(const float4*)&x[row * EMB_DIM + c];
    float a[4] = {v.x, v.y, v.z, v.w};
    unsigned short hb[4], lb[4];
    float s = 0.f;
    #pragma unroll
    for (int i = 0; i < 4; ++i) {
        __half h = __float2half(a[i]);
        __half l = __float2half(a[i] - __half2float(h));
        hb[i] = __half_as_ushort(h); lb[i] = __half_as_ushort(l);
        s = fmaf(a[i], a[i], s);
    }
    *(ushort4*)&xh[row * EMB_DIM + c] = make_ushort4(hb[0], hb[1], hb[2], hb[3]);
    *(ushort4*)&xl[row * EMB_DIM + c] = make_ushort4(lb[0], lb[1], lb[2], lb[3]);
    #pragma unroll
    for (int o = 32; o > 0; o >>= 1) s += __shfl_down(s, o, 64);
    if ((t & 63) == 0) xsq[row] = s;
}

// ---------- main: MFMA distance + per-row argmin with gap tracking ----------
// 512 blocks x 256 thr. Block = 128 rows; loops 16 n-tiles of 128 cols, K=256.
// sim = hi.hi + hi.lo + lo.hi (fp16 split), dist = (xsq+esq) - 2*sim.
__global__ __launch_bounds__(256, 2) void argmin_mfma(
    const __half* __restrict__ xh_, const __half* __restrict__ xl_,
    const __half* __restrict__ cbh_, const __half* __restrict__ cbl_,
    const float* __restrict__ xsq, const float* __restrict__ esq,
    int* __restrict__ idx_out, int* __restrict__ cnt, int* __restrict__ flg) {

    __shared__ float smemf[12288];                 // 48 KB
    _Float16* sa_hi = (_Float16*)smemf;            // [128][32]
    _Float16* sa_lo = sa_hi + 4096;
    _Float16* sb_hi = sa_hi + 8192;                // [128 n][32 k]
    _Float16* sb_lo = sa_hi + 12288;

    const _Float16* xh  = (const _Float16*)xh_;
    const _Float16* xl  = (const _Float16*)xl_;
    const _Float16* cbh = (const _Float16*)cbh_;
    const _Float16* cbl = (const _Float16*)cbl_;

    const int t = threadIdx.x;
    const int w = t >> 6, L = t & 63;
    const int wm = (w >> 1) * 64, wn = (w & 1) * 64;
    const int lm = L & 15, lq = L >> 4;
    const int ph = (lm >> 1) & 3;                  // frag-read XOR swizzle phase
    const int rowbase = blockIdx.x * 128;

    // staging geometry: wave w stages 16 rows at r0 (instr 0) and r1 (instr 1)
    const int srow = L >> 2;                       // row within 16-row group
    const int sq   = (L & 3) ^ ((L >> 3) & 3);     // swizzled source chunk (x8 f16)
    const int r0 = w * 16, r1 = w * 16 + 64;

    float best[16], b2[16], xsr[16];
    int   bi[16];
    #pragma unroll
    for (int s = 0; s < 16; ++s) { best[s] = 3.4e38f; b2[s] = 3.4e38f; bi[s] = 0; }
    #pragma unroll
    for (int f = 0; f < 4; ++f)
        #pragma unroll
        for (int r = 0; r < 4; ++r)
            xsr[f * 4 + r] = xsq[rowbase + wm + f * 16 + lq * 4 + r];

    for (int nt = 0; nt < 16; ++nt) {
        f32x4 acc[4][4];
        #pragma unroll
        for (int f = 0; f < 4; ++f)
            #pragma unroll
            for (int g = 0; g < 4; ++g)
                acc[f][g] = (f32x4){0.f, 0.f, 0.f, 0.f};

        const _Float16* bh = cbh + (size_t)nt * 128 * EMB_DIM;
        const _Float16* bl = cbl + (size_t)nt * 128 * EMB_DIM;

        for (int kt = 0; kt < 8; ++kt) {
            __syncthreads();   // WAR: previous frag reads done before restage
            const int ko = kt * 32 + sq * 8;
            gl_lds16(xh + (size_t)(rowbase + r0 + srow) * EMB_DIM + ko, sa_hi + r0 * 32);
            gl_lds16(xh + (size_t)(rowbase + r1 + srow) * EMB_DIM + ko, sa_hi + r1 * 32);
            gl_lds16(xl + (size_t)(rowbase + r0 + srow) * EMB_DIM + ko, sa_lo + r0 * 32);
            gl_lds16(xl + (size_t)(rowbase + r1 + srow) * EMB_DIM + ko, sa_lo + r1 * 32);
            gl_lds16(bh + (size_t)(r0 + srow) * EMB_DIM + ko, sb_hi + r0 * 32);
            gl_lds16(bh + (size_t)(r1 + srow) * EMB_DIM + ko, sb_hi + r1 * 32);
            gl_lds16(bl + (size_t)(r0 + srow) * EMB_DIM + ko, sb_lo + r0 * 32);
            gl_lds16(bl + (size_t)(r1 + srow) * EMB_DIM + ko, sb_lo + r1 * 32);
            __syncthreads();   // RAW: staged data visible (vmcnt drained)

            half8 ah[4], al[4], bhf[4], blf[4];
            #pragma unroll
            for (int f = 0; f < 4; ++f) {
                int off = (wm + f * 16 + lm) * 32 + ((lq ^ ph) * 8);
                ah[f] = *(const half8*)&sa_hi[off];
                al[f] = *(const half8*)&sa_lo[off];
            }
            #pragma unroll
            for (int g = 0; g < 4; ++g) {
                int off = (wn + g * 16 + lm) * 32 + ((lq ^ ph) * 8);
                bhf[g] = *(const half8*)&sb_hi[off];
                blf[g] = *(const half8*)&sb_lo[off];
            }
            #pragma unroll
            for (int f = 0; f < 4; ++f)
                #pragma unroll
                for (int g = 0; g < 4; ++g) {
                    acc[f][g] = __builtin_amdgcn_mfma_f32_16x16x32_f16(ah[f], bhf[g], acc[f][g], 0, 0, 0);
                    acc[f][g] = __builtin_amdgcn_mfma_f32_16x16x32_f16(ah[f], blf[g], acc[f][g], 0, 0, 0);
                    acc[f][g] = __builtin_amdgcn_mfma_f32_16x16x32_f16(al[f], bhf[g], acc[f][g], 0, 0, 0);
                }
        }

        // epilogue: dist + running (best, second, index); cols ascend -> strict <
        #pragma unroll
        for (int g = 0; g < 4; ++g) {
            int col = nt * 128 + wn + g * 16 + lm;
            float eq = esq[col];
            #pragma unroll
            for (int f = 0; f < 4; ++f)
                #pragma unroll
                for (int r = 0; r < 4; ++r) {
                    int s = f * 4 + r;
                    float d = (xsr[s] + eq) - 2.0f * acc[f][g][r];
                    if (d < best[s]) { b2[s] = best[s]; best[s] = d; bi[s] = col; }
                    else if (d < b2[s]) b2[s] = d;
                }
        }
    }

    // block-level reduce: 32 candidates per row
    __syncthreads();
    float* rd = smemf;                 // [128][32]
    int*   ri = (int*)(smemf + 4096);
    float* r2 = smemf + 8192;
    #pragma unroll
    for (int f = 0; f < 4; ++f)
        #pragma unroll
        for (int r = 0; r < 4; ++r) {
            int row = wm + f * 16 + lq * 4 + r;
            int c = (w & 1) * 16 + lm;
            rd[row * 32 + c] = best[f * 4 + r];
            ri[row * 32 + c] = bi[f * 4 + r];
            r2[row * 32 + c] = b2[f * 4 + r];
        }
    __syncthreads();
    if (t < 128) {
        int row = t;
        float g1 = rd[row * 32]; int gi = ri[row * 32]; float g2 = r2[row * 32];
        for (int c = 1; c < 32; ++c) {
            float d = rd[row * 32 + c]; int ic = ri[row * 32 + c]; float d2 = r2[row * 32 + c];
            if (d < g1 || (d == g1 && ic < gi)) { g2 = fminf(g1, d2); g1 = d; gi = ic; }
            else g2 = fminf(g2, d);
        }
        idx_out[rowbase + row] = gi;
        if (g2 - g1 < EPS_GAP) {       // near-tie: route to exact fp32 fallback
            int p = atomicAdd(cnt, 1);
            flg[p] = rowbase + row;
        }
    }
}

// ---------- exact fp32 re-check for flagged (near-tie) rows ----------
__global__ __launch_bounds__(256) void fallback_k(const float* __restrict__ x,
                                                  const float* __restrict__ cbT,
                                                  const float* __restrict__ xsq,
                                                  const float* __restrict__ esq,
                                                  const int* __restrict__ cnt,
                                                  const int* __restrict__ rows,
                                                  int* __restrict__ idx) {
    __shared__ float xr[256];
    __shared__ float sd[256];
    __shared__ int   si[256];
    int t = threadIdx.x;
    int n = *cnt;
    for (int fi = blockIdx.x; fi < n; fi += gridDim.x) {
        int row = rows[fi];
        __syncthreads();
        xr[t] = x[row * EMB_DIM + t];
        __syncthreads();
        float bd = 3.4e38f; int bi = 0x7fffffff;
        float xq = xsq[row];
        for (int e = t; e < NUM_EMB; e += 256) {
            const float* cr = &cbT[(size_t)e * EMB_DIM];
            float s0 = 0.f, s1 = 0.f, s2 = 0.f, s3 = 0.f;
            for (int d = 0; d < EMB_DIM; d += 4) {
                s0 = fmaf(xr[d], cr[d], s0);
                s1 = fmaf(xr[d + 1], cr[d + 1], s1);
                s2 = fmaf(xr[d + 2], cr[d + 2], s2);
                s3 = fmaf(xr[d + 3], cr[d + 3], s3);
            }
            float sim = (s0 + s1) + (s2 + s3);
            float dd = (xq + esq[e]) - 2.0f * sim;
            if (dd < bd) { bd = dd; bi = e; }   // e ascends per thread
        }
        sd[t] = bd; si[t] = bi;
        __syncthreads();
        for (int stp = 128; stp > 0; stp >>= 1) {
            if (t < stp) {
                if (sd[t + stp] < sd[t] || (sd[t + stp] == sd[t] && si[t + stp] < si[t])) {
                    sd[t] = sd[t + stp]; si[t] = si[t + stp];
                }
            }
            __syncthreads();
        }
        if (t == 0) idx[row] = si[0];
    }
}

// ---------- quantize + straight-through + loss partials + histogram ----------
__global__ __launch_bounds__(256) void quant_k(const float* __restrict__ x,
                                               const float* __restrict__ cbT,
                                               const int* __restrict__ idx,
                                               float* __restrict__ out,
                                               float* __restrict__ bkt,
                                               int* __restrict__ hist) {
    int row = blockIdx.x;
    int t = threadIdx.x;
    int e = idx[row];
    float q  = cbT[(size_t)e * EMB_DIM + t];
    float xv = x[row * EMB_DIM + t];
    out[row * EMB_DIM + t] = xv + (q - xv);
    float diff = xv - q;
    float val = diff * diff;
    #pragma unroll
    for (int o = 32; o > 0; o >>= 1) val += __shfl_down(val, o, 64);
    __shared__ float wsum[4];
    if ((t & 63) == 0) wsum[t >> 6] = val;
    __syncthreads();
    if (t == 0) {
        float s = (wsum[0] + wsum[1]) + (wsum[2] + wsum[3]);
        atomicAdd(&bkt[row & 255], s);
        atomicAdd(&hist[e], 1);
    }
}

// ---------- finalize loss + perplexity ----------
__global__ __launch_bounds__(256) void final_k(const float* __restrict__ bkt,
                                               const int* __restrict__ hist,
                                               float* __restrict__ out) {
    int t = threadIdx.x;
    double ls = (double)bkt[t];
    double ps = 0.0;
    for (int i = t; i < NUM_EMB; i += 256) {
        double p = (double)hist[i] / (double)N_ROWS;
        ps += p * log(p + 1e-10);
    }
    __shared__ double sdd[256], spp[256];
    sdd[t] = ls; spp[t] = ps;
    __syncthreads();
    for (int s = 128; s > 0; s >>= 1) {
        if (t < s) { sdd[t] += sdd[t + s]; spp[t] += spp[t + s]; }
        __syncthreads();
    }
    if (t == 0) {
        out[N_ELEM + 0] = (float)(1.25 * sdd[0] / (double)N_ELEM);
        out[N_ELEM + 1] = (float)exp(-spp[0]);
    }
}

extern "C" void kernel_launch(void* const* d_in, const int* in_sizes, int n_in,
                              void* d_out, int out_size, void* d_ws, size_t ws_size,
                              hipStream_t stream) {
    const float* x  = (const float*)d_in[0];
    const float* cb = (const float*)d_in[1];
    float* out = (float*)d_out;

    float* ws_f = (float*)d_ws;
    int*   ws_i = (int*)d_ws;
    int*   idx  = ws_i + IDX_OFF;
    float* xsq  = ws_f + XSQ_OFF;
    float* esq  = ws_f + ESQ_OFF;
    int*   hist = ws_i + HIST_OFF;
    float* bkt  = ws_f + BKT_OFF;
    int*   cnt  = ws_i + CNT_OFF;
    int*   flg  = ws_i + FLG_OFF;
    float* cbT  = ws_f + CBT_OFF;
    __half* cbTh = (__half*)(ws_f + CBTH_OFF);
    __half* cbTl = (__half*)(ws_f + CBTL_OFF);

    // x hi/lo fp16 planes live in d_out (overwritten by quant_k at the end)
    __half* xh = (__half*)d_out;
    __half* xl = (__half*)((char*)d_out + 33554432);

    hipMemsetAsync((char*)d_ws + (size_t)HIST_OFF * 4, 0,
                   (NUM_EMB + 256 + 1) * sizeof(float), stream);

    esq_k<<<NUM_EMB / 256, 256, 0, stream>>>(cb, esq);
    prep_cbt<<<128, 256, 0, stream>>>(cb, cbT, cbTh, cbTl);
    prep_x<<<N_ROWS / 4, 256, 0, stream>>>(x, xh, xl, xsq);
    argmin_mfma<<<N_ROWS / 128, 256, 0, stream>>>(xh, xl, cbTh, cbTl, xsq, esq, idx, cnt, flg);
    fallback_k<<<128, 256, 0, stream>>>(x, cbT, xsq, esq, cnt, flg, idx);
    quant_k<<<N_ROWS, 256, 0, stream>>>(x, cbT, idx, out, bkt, hist);
    final_k<<<1, 256, 0, stream>>>(bkt, hist, out);
}